// Round 14
// baseline (31.015 us; speedup 1.0000x reference)
//
#include <hip/hip_runtime.h>
#include <hip/hip_fp16.h>

// Problem constants
#define BB 512      // batch
#define FF 1024     // features (= K of GEMM, = NK*KD)
#define NK 64       // num kernels
#define KD 16       // kernel dim

typedef __attribute__((ext_vector_type(4))) float f32x4;
typedef __attribute__((ext_vector_type(2))) float f32x2;
typedef __attribute__((ext_vector_type(8))) _Float16 half8;
typedef __attribute__((ext_vector_type(8))) unsigned short ushort8;

__device__ __forceinline__ unsigned short f16_bits(float f) {
    __half h = __float2half(f);   // RNE
    return *reinterpret_cast<unsigned short*>(&h);
}

// ---------------------------------------------------------------------------
// FUSED prep+GEMM (R10/R13-verified, unchanged): f32 x,T -> in-reg f16 ->
// swizzled LDS -> MFMA. BM=32,BN=32,BK=64; 512 blocks, 256 thr, dbuf.
// Blocks 0..3 zero `out`. Output M2[kblk][512][16] f32.
// ---------------------------------------------------------------------------
__global__ __launch_bounds__(256) void md_mfma_fused_kernel(
    const float* __restrict__ x, const float* __restrict__ T,
    float* __restrict__ M2, float* __restrict__ out) {
    __shared__ __align__(16) unsigned short lds[2][4096];

    const int t = threadIdx.x, w = t >> 6, l = t & 63;
    const int b = blockIdx.x, xc = b & 7, r = b >> 3;
    const int nt = xc * 4 + (r & 3);           // 0..31 (32-col n-tile)
    const int mt = r >> 2;                     // 0..15 (32-row m-tile)

    if (b < 4) {
        const float4 z = make_float4(0.f, 0.f, 0.f, 0.f);
        #pragma unroll
        for (int q = 0; q < 8; ++q)
            *(float4*)&out[(size_t)(b * 2048 + q * 256 + t) * 4] = z;
    }

    const int rowA = t >> 3, k8 = t & 7;
    const float* gA = x + (size_t)(mt * 32 + rowA) * FF + k8 * 8;
    const int wA = rowA * 64 + ((k8 ^ (rowA & 7)) * 8);   // swizzled ushort idx

    const int k2 = (t >> 3) * 2, nB = (t & 7) * 4;
    const float* gB = T + (size_t)k2 * FF + nt * 32 + nB;
    const int c16B = ((k2 >> 3) * 8);

    const int lrow = l & 15, lkg = l >> 4;
    const int ar = (w >> 1) * 16 + lrow;       // A row 0..31
    const int br = (w & 1) * 16 + lrow;        // B row 0..31
    const int swa = ar & 7, swb = br & 7;

    f32x4 acc = {};
    float4 a0[2], a1[2], b0[2], b1[2];

#define LOADT(s, it_) do {                                                  \
        a0[s] = *(const float4*)(gA + (it_) * 64);                          \
        a1[s] = *(const float4*)(gA + (it_) * 64 + 4);                      \
        b0[s] = *(const float4*)(gB + (size_t)(it_) * 64 * FF);             \
        b1[s] = *(const float4*)(gB + (size_t)(it_) * 64 * FF + FF);        \
    } while (0)

#define CVTW(s, bf) do {                                                    \
        ushort8 hv;                                                         \
        hv[0] = f16_bits(a0[s].x); hv[1] = f16_bits(a0[s].y);               \
        hv[2] = f16_bits(a0[s].z); hv[3] = f16_bits(a0[s].w);               \
        hv[4] = f16_bits(a1[s].x); hv[5] = f16_bits(a1[s].y);               \
        hv[6] = f16_bits(a1[s].z); hv[7] = f16_bits(a1[s].w);               \
        *(ushort8*)&lds[bf][wA] = hv;                                       \
        const float q0[4] = {b0[s].x, b0[s].y, b0[s].z, b0[s].w};           \
        const float q1[4] = {b1[s].x, b1[s].y, b1[s].z, b1[s].w};           \
        _Pragma("unroll")                                                   \
        for (int j = 0; j < 4; ++j) {                                       \
            const unsigned int pk = (unsigned int)f16_bits(q0[j]) |         \
                                    ((unsigned int)f16_bits(q1[j]) << 16);  \
            const int n = nB + j;                                           \
            *(unsigned int*)&lds[bf][2048 + n * 64 +                        \
                (c16B ^ ((n & 7) * 8)) + (k2 & 7)] = pk;                    \
        }                                                                   \
    } while (0)

    LOADT(0, 0);
    LOADT(1, 1);
    CVTW(0, 0);
    __syncthreads();

    #pragma unroll
    for (int it = 0; it < 16; ++it) {
        const int s = it & 1;
        if (it + 2 < 16) LOADT(s, it + 2);
        const unsigned short* L = lds[s];
        #pragma unroll
        for (int ks = 0; ks < 2; ++ks) {
            const int cb = ks * 4 + lkg;
            const half8 af = *(const half8*)&L[ar * 64 + ((cb ^ swa) * 8)];
            const half8 bf = *(const half8*)&L[2048 + br * 64 + ((cb ^ swb) * 8)];
            acc = __builtin_amdgcn_mfma_f32_16x16x32_f16(af, bf, acc, 0, 0, 0);
        }
        if (it + 1 < 16) {
            CVTW(s ^ 1, s ^ 1);
            __syncthreads();
        }
    }
#undef LOADT
#undef CVTW

    const int kblk = nt * 2 + (w & 1);           // 0..63
    const int rowb = mt * 32 + (w >> 1) * 16 + lkg * 4;
    #pragma unroll
    for (int rg = 0; rg < 4; ++rg)
        M2[((size_t)kblk * BB + rowb + rg) * KD + lrow] = acc[rg];
}

// ---------------------------------------------------------------------------
// Symmetric pairwise v4: R13 structure (scalar-uniform mj from global,
// XCD-local k) + PACKED f32 inner loop: 16 subs -> 8 v_pk_add_f32(neg),
// abs folded into scalar adds, full jj unroll for immediate offsets.
// Arithmetic values/order bit-identical to R13.
// ---------------------------------------------------------------------------
__global__ __launch_bounds__(256) void md_pairwise_sym_kernel(
    const float* __restrict__ M2, float* __restrict__ out) {
    __shared__ float et[64][65];
    __shared__ float part_row[4][64];
    __shared__ float part_col[4][64];

    const int bx = blockIdx.x;
    const int k = ((bx & 7) << 3) | ((bx >> 3) & 7);   // XCD-local k
    int p = bx >> 6;
    int it = 0;
    while (p >= 8 - it) { p -= 8 - it; ++it; }
    const int jt = it + p;
    const bool diag = (it == jt);
    const int t = threadIdx.x;

    const float* tileI = M2 + ((size_t)k * BB + it * 64) * KD;
    const float* tileJ = M2 + ((size_t)k * BB + jt * 64) * KD;

    const int i = t & 63;
    const int wv = t >> 6;

    // mi as 8 register pairs (f32x2) for packed subs
    f32x2 mi2[8];
    #pragma unroll
    for (int dg = 0; dg < 4; ++dg) {
        const float4 v = *(const float4*)&tileI[i * KD + dg * 4];
        mi2[dg * 2 + 0] = (f32x2){v.x, v.y};
        mi2[dg * 2 + 1] = (f32x2){v.z, v.w};
    }

    float row_acc = 0.0f;
    #pragma unroll
    for (int jj = 0; jj < 16; ++jj) {
        const int j = wv * 16 + jj;
        // wave-uniform offset -> scalar/uniform loads (R13-verified)
        const int off = __builtin_amdgcn_readfirstlane(j * KD);
        const float4 v0 = *(const float4*)(tileJ + off);
        const float4 v1 = *(const float4*)(tileJ + off + 4);
        const float4 v2 = *(const float4*)(tileJ + off + 8);
        const float4 v3 = *(const float4*)(tileJ + off + 12);

        // 8 packed subs (v_pk_add_f32 with neg) replacing 16 scalar subs
        const f32x2 t0 = mi2[0] - (f32x2){v0.x, v0.y};
        const f32x2 t1 = mi2[1] - (f32x2){v0.z, v0.w};
        const f32x2 t2 = mi2[2] - (f32x2){v1.x, v1.y};
        const f32x2 t3 = mi2[3] - (f32x2){v1.z, v1.w};
        const f32x2 t4 = mi2[4] - (f32x2){v2.x, v2.y};
        const f32x2 t5 = mi2[5] - (f32x2){v2.z, v2.w};
        const f32x2 t6 = mi2[6] - (f32x2){v3.x, v3.y};
        const f32x2 t7 = mi2[7] - (f32x2){v3.z, v3.w};

        // abs folds into v_add |a|,|b| (VOP3 input modifiers)
        const float p0 = fabsf(t0.x) + fabsf(t0.y);
        const float p1 = fabsf(t1.x) + fabsf(t1.y);
        const float p2 = fabsf(t2.x) + fabsf(t2.y);
        const float p3 = fabsf(t3.x) + fabsf(t3.y);
        const float p4 = fabsf(t4.x) + fabsf(t4.y);
        const float p5 = fabsf(t5.x) + fabsf(t5.y);
        const float p6 = fabsf(t6.x) + fabsf(t6.y);
        const float p7 = fabsf(t7.x) + fabsf(t7.y);

        const float l1 = ((p0 + p1) + (p2 + p3)) + ((p4 + p5) + (p6 + p7));
        const float e = __expf(-l1);
        row_acc += e;
        et[i][j] = e;                    // const jj -> immediate ds offset
    }
    part_row[wv][i] = row_acc;
    __syncthreads();

    if (!diag) {
        const int j = t & 63;
        const int chunk = t >> 6;
        float col_acc = 0.0f;
        #pragma unroll
        for (int ii = 0; ii < 16; ++ii)
            col_acc += et[chunk * 16 + ii][j];
        part_col[chunk][j] = col_acc;
    }
    __syncthreads();

    if (t < 64) {
        float rr = ((part_row[0][t] + part_row[1][t]) +
                    (part_row[2][t] + part_row[3][t])) - (diag ? 1.0f : 0.0f);
        atomicAdd(&out[(size_t)(it * 64 + t) * NK + k], rr);
    } else if (t < 128 && !diag) {
        const int j = t - 64;
        float c = (part_col[0][j] + part_col[1][j]) +
                  (part_col[2][j] + part_col[3][j]);
        atomicAdd(&out[(size_t)(jt * 64 + j) * NK + k], c);
    }
}

extern "C" void kernel_launch(void* const* d_in, const int* in_sizes, int n_in,
                              void* d_out, int out_size, void* d_ws, size_t ws_size,
                              hipStream_t stream) {
    const float* x = (const float*)d_in[0];   // [512, 1024] f32
    const float* T = (const float*)d_in[1];   // [1024, 1024] f32
    float* out = (float*)d_out;               // [512, 64] f32

    float* M2 = (float*)d_ws;                 // [64][512][16] f32 (2 MB)

    md_mfma_fused_kernel<<<dim3(512), 256, 0, stream>>>(x, T, M2, out);
    md_pairwise_sym_kernel<<<dim3(36 * 64), 256, 0, stream>>>(M2, out);
}

// Round 15
// 29.206 us; speedup vs baseline: 1.0619x; 1.0619x over previous
//
#include <hip/hip_runtime.h>
#include <hip/hip_fp16.h>

// Problem constants
#define BB 512      // batch
#define FF 1024     // features (= K of GEMM, = NK*KD)
#define NK 64       // num kernels
#define KD 16       // kernel dim

typedef __attribute__((ext_vector_type(4))) float f32x4;
typedef __attribute__((ext_vector_type(2))) float f32x2;
typedef __attribute__((ext_vector_type(8))) _Float16 half8;
typedef __attribute__((ext_vector_type(8))) unsigned short ushort8;

__device__ __forceinline__ unsigned short f16_bits(float f) {
    __half h = __float2half(f);   // RNE
    return *reinterpret_cast<unsigned short*>(&h);
}

// ---------------------------------------------------------------------------
// FUSED prep+GEMM (R10/R13-verified, unchanged): f32 x,T -> in-reg f16 ->
// swizzled LDS -> MFMA. BM=32,BN=32,BK=64; 512 blocks, 256 thr, dbuf.
// Blocks 0..3 zero `out`. Output M2[kblk][512][16] f32.
// ---------------------------------------------------------------------------
__global__ __launch_bounds__(256) void md_mfma_fused_kernel(
    const float* __restrict__ x, const float* __restrict__ T,
    float* __restrict__ M2, float* __restrict__ out) {
    __shared__ __align__(16) unsigned short lds[2][4096];

    const int t = threadIdx.x, w = t >> 6, l = t & 63;
    const int b = blockIdx.x, xc = b & 7, r = b >> 3;
    const int nt = xc * 4 + (r & 3);           // 0..31 (32-col n-tile)
    const int mt = r >> 2;                     // 0..15 (32-row m-tile)

    if (b < 4) {
        const float4 z = make_float4(0.f, 0.f, 0.f, 0.f);
        #pragma unroll
        for (int q = 0; q < 8; ++q)
            *(float4*)&out[(size_t)(b * 2048 + q * 256 + t) * 4] = z;
    }

    const int rowA = t >> 3, k8 = t & 7;
    const float* gA = x + (size_t)(mt * 32 + rowA) * FF + k8 * 8;
    const int wA = rowA * 64 + ((k8 ^ (rowA & 7)) * 8);   // swizzled ushort idx

    const int k2 = (t >> 3) * 2, nB = (t & 7) * 4;
    const float* gB = T + (size_t)k2 * FF + nt * 32 + nB;
    const int c16B = ((k2 >> 3) * 8);

    const int lrow = l & 15, lkg = l >> 4;
    const int ar = (w >> 1) * 16 + lrow;       // A row 0..31
    const int br = (w & 1) * 16 + lrow;        // B row 0..31
    const int swa = ar & 7, swb = br & 7;

    f32x4 acc = {};
    float4 a0[2], a1[2], b0[2], b1[2];

#define LOADT(s, it_) do {                                                  \
        a0[s] = *(const float4*)(gA + (it_) * 64);                          \
        a1[s] = *(const float4*)(gA + (it_) * 64 + 4);                      \
        b0[s] = *(const float4*)(gB + (size_t)(it_) * 64 * FF);             \
        b1[s] = *(const float4*)(gB + (size_t)(it_) * 64 * FF + FF);        \
    } while (0)

#define CVTW(s, bf) do {                                                    \
        ushort8 hv;                                                         \
        hv[0] = f16_bits(a0[s].x); hv[1] = f16_bits(a0[s].y);               \
        hv[2] = f16_bits(a0[s].z); hv[3] = f16_bits(a0[s].w);               \
        hv[4] = f16_bits(a1[s].x); hv[5] = f16_bits(a1[s].y);               \
        hv[6] = f16_bits(a1[s].z); hv[7] = f16_bits(a1[s].w);               \
        *(ushort8*)&lds[bf][wA] = hv;                                       \
        const float q0[4] = {b0[s].x, b0[s].y, b0[s].z, b0[s].w};           \
        const float q1[4] = {b1[s].x, b1[s].y, b1[s].z, b1[s].w};           \
        _Pragma("unroll")                                                   \
        for (int j = 0; j < 4; ++j) {                                       \
            const unsigned int pk = (unsigned int)f16_bits(q0[j]) |         \
                                    ((unsigned int)f16_bits(q1[j]) << 16);  \
            const int n = nB + j;                                           \
            *(unsigned int*)&lds[bf][2048 + n * 64 +                        \
                (c16B ^ ((n & 7) * 8)) + (k2 & 7)] = pk;                    \
        }                                                                   \
    } while (0)

    LOADT(0, 0);
    LOADT(1, 1);
    CVTW(0, 0);
    __syncthreads();

    #pragma unroll
    for (int it = 0; it < 16; ++it) {
        const int s = it & 1;
        if (it + 2 < 16) LOADT(s, it + 2);
        const unsigned short* L = lds[s];
        #pragma unroll
        for (int ks = 0; ks < 2; ++ks) {
            const int cb = ks * 4 + lkg;
            const half8 af = *(const half8*)&L[ar * 64 + ((cb ^ swa) * 8)];
            const half8 bf = *(const half8*)&L[2048 + br * 64 + ((cb ^ swb) * 8)];
            acc = __builtin_amdgcn_mfma_f32_16x16x32_f16(af, bf, acc, 0, 0, 0);
        }
        if (it + 1 < 16) {
            CVTW(s ^ 1, s ^ 1);
            __syncthreads();
        }
    }
#undef LOADT
#undef CVTW

    const int kblk = nt * 2 + (w & 1);           // 0..63
    const int rowb = mt * 32 + (w >> 1) * 16 + lkg * 4;
    #pragma unroll
    for (int rg = 0; rg < 4; ++rg)
        M2[((size_t)kblk * BB + rowb + rg) * KD + lrow] = acc[rg];
}

// ---------------------------------------------------------------------------
// Symmetric pairwise v5 = R13 verbatim + ONE change: packed f32x2 subs
// (v_pk_add_f32 w/ neg) replacing 16 scalar subs. unroll 4 kept (R14's
// full unroll caused the regression). Arithmetic bit-identical to R13.
// ---------------------------------------------------------------------------
__global__ __launch_bounds__(256) void md_pairwise_sym_kernel(
    const float* __restrict__ M2, float* __restrict__ out) {
    __shared__ float et[64][65];
    __shared__ float part_row[4][64];
    __shared__ float part_col[4][64];

    const int bx = blockIdx.x;
    const int k = ((bx & 7) << 3) | ((bx >> 3) & 7);   // XCD-local k
    int p = bx >> 6;
    int it = 0;
    while (p >= 8 - it) { p -= 8 - it; ++it; }
    const int jt = it + p;
    const bool diag = (it == jt);
    const int t = threadIdx.x;

    const float* tileI = M2 + ((size_t)k * BB + it * 64) * KD;
    const float* tileJ = M2 + ((size_t)k * BB + jt * 64) * KD;

    const int i = t & 63;
    const int wv = t >> 6;

    // mi as 8 register pairs for packed subs
    f32x2 mi2[8];
    #pragma unroll
    for (int dg = 0; dg < 4; ++dg) {
        const float4 v = *(const float4*)&tileI[i * KD + dg * 4];
        mi2[dg * 2 + 0] = (f32x2){v.x, v.y};
        mi2[dg * 2 + 1] = (f32x2){v.z, v.w};
    }

    float row_acc = 0.0f;
    #pragma unroll 4
    for (int jj = 0; jj < 16; ++jj) {
        const int j = wv * 16 + jj;
        // wave-uniform offset -> scalar/uniform loads (R13-verified)
        const int off = __builtin_amdgcn_readfirstlane(j * KD);
        const float4 v0 = *(const float4*)(tileJ + off);
        const float4 v1 = *(const float4*)(tileJ + off + 4);
        const float4 v2 = *(const float4*)(tileJ + off + 8);
        const float4 v3 = *(const float4*)(tileJ + off + 12);

        const f32x2 t0 = mi2[0] - (f32x2){v0.x, v0.y};
        const f32x2 t1 = mi2[1] - (f32x2){v0.z, v0.w};
        const f32x2 t2 = mi2[2] - (f32x2){v1.x, v1.y};
        const f32x2 t3 = mi2[3] - (f32x2){v1.z, v1.w};
        const f32x2 t4 = mi2[4] - (f32x2){v2.x, v2.y};
        const f32x2 t5 = mi2[5] - (f32x2){v2.z, v2.w};
        const f32x2 t6 = mi2[6] - (f32x2){v3.x, v3.y};
        const f32x2 t7 = mi2[7] - (f32x2){v3.z, v3.w};

        const float p0 = fabsf(t0.x) + fabsf(t0.y);
        const float p1 = fabsf(t1.x) + fabsf(t1.y);
        const float p2 = fabsf(t2.x) + fabsf(t2.y);
        const float p3 = fabsf(t3.x) + fabsf(t3.y);
        const float p4 = fabsf(t4.x) + fabsf(t4.y);
        const float p5 = fabsf(t5.x) + fabsf(t5.y);
        const float p6 = fabsf(t6.x) + fabsf(t6.y);
        const float p7 = fabsf(t7.x) + fabsf(t7.y);

        const float l1 = ((p0 + p1) + (p2 + p3)) + ((p4 + p5) + (p6 + p7));
        const float e = __expf(-l1);
        row_acc += e;
        et[i][j] = e;                    // banks (i+j)%32 -> conflict-free
    }
    part_row[wv][i] = row_acc;
    __syncthreads();

    if (!diag) {
        const int j = t & 63;
        const int chunk = t >> 6;
        float col_acc = 0.0f;
        #pragma unroll
        for (int ii = 0; ii < 16; ++ii)
            col_acc += et[chunk * 16 + ii][j];
        part_col[chunk][j] = col_acc;
    }
    __syncthreads();

    if (t < 64) {
        float rr = ((part_row[0][t] + part_row[1][t]) +
                    (part_row[2][t] + part_row[3][t])) - (diag ? 1.0f : 0.0f);
        atomicAdd(&out[(size_t)(it * 64 + t) * NK + k], rr);
    } else if (t < 128 && !diag) {
        const int j = t - 64;
        float c = (part_col[0][j] + part_col[1][j]) +
                  (part_col[2][j] + part_col[3][j]);
        atomicAdd(&out[(size_t)(jt * 64 + j) * NK + k], c);
    }
}

extern "C" void kernel_launch(void* const* d_in, const int* in_sizes, int n_in,
                              void* d_out, int out_size, void* d_ws, size_t ws_size,
                              hipStream_t stream) {
    const float* x = (const float*)d_in[0];   // [512, 1024] f32
    const float* T = (const float*)d_in[1];   // [1024, 1024] f32
    float* out = (float*)d_out;               // [512, 64] f32

    float* M2 = (float*)d_ws;                 // [64][512][16] f32 (2 MB)

    md_mfma_fused_kernel<<<dim3(512), 256, 0, stream>>>(x, T, M2, out);
    md_pairwise_sym_kernel<<<dim3(36 * 64), 256, 0, stream>>>(M2, out);
}